// Round 8
// baseline (308.940 us; speedup 1.0000x reference)
//
#include <hip/hip_runtime.h>
#include <hip/hip_bf16.h>
#include <cstdint>

// KAN MLP: 256->512->512->256, B=8192, cubic B-splines (uniform grid h=0.25,
// knots -1.75..1.75, 11 bases), BN at the end.
//
// Round-8 = round-7 with a 256x128 GEMM tile (staging-BW theory):
//  - tile 256(M) x 128(N), 512 threads = 8 waves (4x2 of 64x64), BK=64
//    -> 192 B staged per MFMA (was 256 B at 128x128): -25% L2 staging
//  - SK=4/4/8 -> every grid 512 blocks = 2 blocks/CU = 16 waves/CU
//  - per-wave fragment maps + XOR swizzle byte-identical to the verified
//    0-conflict round-4/6/7 core
//  - partials bf16 (round-7, verified absmax 0.0098 << 0.035)
//
// Workspace (145,227,776 bytes <= 146,800,640 proven):
//   A   @ 0          : 8192*6144*2 = 100,663,296 (reused all layers)
//   W0  @ 100663296  : 3,145,728
//   W1  @ 103809024  : 6,291,456
//   W2  @ 110100480  : 3,145,728
//   P   @ 113246208  : 32 MB partial region:
//                      L0/L1: 4 x 8 MB bf16 (stride 8192*512)
//                      L2   : 8 x 4 MB bf16 (stride 8192*256)

typedef unsigned short ushort_t;
typedef __bf16 bf16x8 __attribute__((ext_vector_type(8)));
typedef float f32x4 __attribute__((ext_vector_type(4)));

__device__ __forceinline__ ushort_t f2bf(float f) {
    __bf16 h = (__bf16)f;  // RNE
    return __builtin_bit_cast(ushort_t, h);
}
__device__ __forceinline__ float bf2f(ushort_t u) {
    unsigned int v = ((unsigned int)u) << 16;
    return __builtin_bit_cast(float, v);
}

// async global->LDS 16B copy; LDS dest must be wave-uniform base + lane*16.
__device__ __forceinline__ void gload_lds16(const void* g, void* lds) {
    __builtin_amdgcn_global_load_lds(
        (const __attribute__((address_space(1))) unsigned int*)(uintptr_t)g,
        (__attribute__((address_space(3))) unsigned int*)(unsigned int)(uintptr_t)lds,
        16, 0, 0);
}

// x -> [gelu, b0..b10] (12 bf16). Direct cardinal cubic B-spline (verified
// rounds 3-7, absmax <= 0.0098): b(t), a=|t-2|: a<=1: (4-6a^2+3a^3)/6;
// 1<a<2: (2-a)^3/6; else 0.
__device__ __forceinline__ void expand12(float x, ushort_t* o) {
    float x3 = x * x * x;
    float y  = 0.7978845608028654f * (x + 0.044715f * x3);
    float e  = __expf(2.0f * y);
    float th = 1.0f - 2.0f / (e + 1.0f);       // tanh(y)
    o[0] = f2bf(0.5f * x * (1.0f + th));
    float xs = (x + 1.75f) * 4.0f;
#pragma unroll
    for (int j = 0; j < 11; ++j) {
        float t  = xs - (float)j;
        float a  = fabsf(t - 2.0f);
        float p1 = (3.0f * a - 6.0f) * a * a + 4.0f;
        float c  = 2.0f - a;
        float p2 = c * c * c;
        float v  = (a <= 1.0f) ? p1 : fmaxf(p2, 0.0f);
        o[1 + j] = f2bf(v * (1.0f / 6.0f));
    }
}

// ---------------------------------------------------------------------------
// prep: blocks [0,2048) pack W0/W1/W2; blocks [2048,4096) expand x -> A.
// ---------------------------------------------------------------------------
__global__ __launch_bounds__(256) void prep_kernel(
    const float* __restrict__ bw0, const float* __restrict__ sw0, ushort_t* __restrict__ W0,
    const float* __restrict__ bw1, const float* __restrict__ sw1, ushort_t* __restrict__ W1,
    const float* __restrict__ bw2, const float* __restrict__ sw2, ushort_t* __restrict__ W2,
    const float* __restrict__ x, ushort_t* __restrict__ A)
{
    int b = blockIdx.x;
    if (b < 2048) {
        int idx = b * 256 + threadIdx.x;   // [0, 524288)
        const float* bw; const float* sw; ushort_t* W; int local;
        if (idx < 131072)      { bw = bw0; sw = sw0; W = W0; local = idx; }
        else if (idx < 393216) { bw = bw1; sw = sw1; W = W1; local = idx - 131072; }
        else                   { bw = bw2; sw = sw2; W = W2; local = idx - 393216; }
        union { ushort_t us[12]; uint2 v[3]; } pk;
        pk.us[0] = f2bf(bw[local]);
        const float* s = sw + (size_t)local * 11;
#pragma unroll
        for (int k = 0; k < 11; ++k) pk.us[1 + k] = f2bf(s[k]);
        uint2* dst = (uint2*)(W + (size_t)local * 12);
        dst[0] = pk.v[0]; dst[1] = pk.v[1]; dst[2] = pk.v[2];
    } else {
        int idx = (b - 2048) * 256 + threadIdx.x;   // [0, 524288) quads
        float4 h = *(const float4*)(x + 4 * (size_t)idx);
        union { ushort_t us[48]; uint4 v[6]; } pk;
        expand12(h.x, pk.us);
        expand12(h.y, pk.us + 12);
        expand12(h.z, pk.us + 24);
        expand12(h.w, pk.us + 36);
        uint4* dst = (uint4*)(A + (size_t)idx * 48);
#pragma unroll
        for (int j = 0; j < 6; ++j) dst[j] = pk.v[j];
    }
}

// ---------------------------------------------------------------------------
// Expansion: h = sum of 4 bf16 partial streams; 4 elems/thread.
// ---------------------------------------------------------------------------
__global__ __launch_bounds__(256) void expand_kernel(
    const ushort_t* __restrict__ P, size_t stride,
    ushort_t* __restrict__ A, int total4)
{
    int idx = blockIdx.x * 256 + threadIdx.x;
    if (idx >= total4) return;
    float h[4] = {0.f, 0.f, 0.f, 0.f};
#pragma unroll
    for (int z = 0; z < 4; ++z) {
        ushort4 p = *(const ushort4*)(P + z * stride + 4 * (size_t)idx);
        h[0] += bf2f(p.x); h[1] += bf2f(p.y); h[2] += bf2f(p.z); h[3] += bf2f(p.w);
    }
    union { ushort_t us[48]; uint4 v[6]; } pk;
    expand12(h[0], pk.us);
    expand12(h[1], pk.us + 12);
    expand12(h[2], pk.us + 24);
    expand12(h[3], pk.us + 36);
    uint4* dst = (uint4*)(A + (size_t)idx * 48);
#pragma unroll
    for (int j = 0; j < 6; ++j) dst[j] = pk.v[j];
}

// ---------------------------------------------------------------------------
// GEMM: C_z = A[M,ksl] @ W[N,ksl]^T, bf16 partials out.
// Tile 256x128, BK=64, 512 threads = 8 waves in 4x2; each wave 64x64
// (4x4 of 16x16x32 MFMA -- per-wave code identical to the verified core).
// LDS: As 256x8, Bs 128x8 chunks of 16B, chunk XOR-swizzled by row&7
// (verified 0 conflicts).  A frag: lane A[m=l15][k=q*8+j]; C/D: D[q*4+r][l15].
// ---------------------------------------------------------------------------
__global__ __launch_bounds__(512, 4) void gemm_kernel(
    const ushort_t* __restrict__ A,  // M x K
    const ushort_t* __restrict__ W,  // N x K
    ushort_t* __restrict__ C,        // split-K bf16 partials, z*M*N apart
    int M, int N, int K, int kcps)   // kcps = 64-chunks per split
{
    __shared__ __align__(16) ushort_t As[256 * 64];  // 32 KB
    __shared__ __align__(16) ushort_t Bs[128 * 64];  // 16 KB

    const int t   = threadIdx.x;
    const int l   = t & 63;
    const int w   = t >> 6;       // 0..7
    const int wm  = w >> 1;       // 0..3 -> +64*wm rows
    const int wn  = w & 1;        // 0..1 -> +64*wn cols
    const int l15 = l & 15;
    const int q   = l >> 4;
    const int blockM = blockIdx.x * 256;
    const int blockN = blockIdx.y * 128;
    const int kb0 = blockIdx.z * kcps, kb1 = kb0 + kcps;
    ushort_t* Cz = C + (size_t)blockIdx.z * M * N;

    f32x4 acc[4][4];
#pragma unroll
    for (int i = 0; i < 4; ++i)
#pragma unroll
        for (int j = 0; j < 4; ++j) acc[i][j] = (f32x4){0.f, 0.f, 0.f, 0.f};

    for (int kb = kb0; kb < kb1; ++kb) {
        const int k0 = kb << 6;
        // stage A: 256 rows x 8 chunks = 2048 chunks, 4/thread
#pragma unroll
        for (int it = 0; it < 4; ++it) {
            int s   = it * 512 + t;
            int row = s >> 3, c = s & 7;
            int g   = c ^ (row & 7);
            gload_lds16(A + ((size_t)(blockM + row) * K + k0 + g * 8), &As[s * 8]);
        }
        // stage B: 128 rows x 8 chunks = 1024 chunks, 2/thread
#pragma unroll
        for (int it = 0; it < 2; ++it) {
            int s   = it * 512 + t;
            int row = s >> 3, c = s & 7;
            int g   = c ^ (row & 7);
            gload_lds16(W + ((size_t)(blockN + row) * K + k0 + g * 8), &Bs[s * 8]);
        }
        __syncthreads();

#pragma unroll
        for (int ks = 0; ks < 2; ++ks) {
            const int kc = ks * 4 + q;
            bf16x8 af[4], bf[4];
#pragma unroll
            for (int mi = 0; mi < 4; ++mi) {
                int m  = wm * 64 + mi * 16 + l15;
                int cs = kc ^ (m & 7);
                af[mi] = *(const bf16x8*)&As[(size_t)(m * 8 + cs) * 8];
            }
#pragma unroll
            for (int ni = 0; ni < 4; ++ni) {
                int n  = wn * 64 + ni * 16 + l15;
                int cs = kc ^ (n & 7);
                bf[ni] = *(const bf16x8*)&Bs[(size_t)(n * 8 + cs) * 8];
            }
#pragma unroll
            for (int mi = 0; mi < 4; ++mi)
#pragma unroll
                for (int ni = 0; ni < 4; ++ni)
                    acc[mi][ni] = __builtin_amdgcn_mfma_f32_16x16x32_bf16(
                        af[mi], bf[ni], acc[mi][ni], 0, 0, 0);
        }
        __syncthreads();
    }

    // epilogue: bf16 partial stores
#pragma unroll
    for (int ni = 0; ni < 4; ++ni) {
        int n = blockN + wn * 64 + ni * 16 + l15;
#pragma unroll
        for (int mi = 0; mi < 4; ++mi) {
            int mb = blockM + wm * 64 + mi * 16 + q * 4;
#pragma unroll
            for (int r = 0; r < 4; ++r)
                Cz[(size_t)(mb + r) * N + n] = f2bf(acc[mi][ni][r]);
        }
    }
}

// ---------------------------------------------------------------------------
// Final: out = gamma*rsqrt(var+eps)*(sum of 8 bf16 partials - mean) + beta.
// ---------------------------------------------------------------------------
__global__ __launch_bounds__(256) void bn_reduce_kernel(
    const ushort_t* __restrict__ P, size_t stride,   // 8 partials
    const float* __restrict__ gamma, const float* __restrict__ beta,
    const float* __restrict__ mean,  const float* __restrict__ var,
    float4* __restrict__ out, int n4)
{
    int i = blockIdx.x * 256 + threadIdx.x;
    if (i >= n4) return;
    float h[4] = {0.f, 0.f, 0.f, 0.f};
#pragma unroll
    for (int z = 0; z < 8; ++z) {
        ushort4 p = *(const ushort4*)(P + z * stride + 4 * (size_t)i);
        h[0] += bf2f(p.x); h[1] += bf2f(p.y); h[2] += bf2f(p.z); h[3] += bf2f(p.w);
    }
    int nb = (i * 4) & 255;
    float4 g  = *(const float4*)(gamma + nb);
    float4 be = *(const float4*)(beta + nb);
    float4 mn = *(const float4*)(mean + nb);
    float4 vr = *(const float4*)(var + nb);
    float4 o;
    o.x = g.x * rsqrtf(vr.x + 1e-5f) * (h[0] - mn.x) + be.x;
    o.y = g.y * rsqrtf(vr.y + 1e-5f) * (h[1] - mn.y) + be.y;
    o.z = g.z * rsqrtf(vr.z + 1e-5f) * (h[2] - mn.z) + be.z;
    o.w = g.w * rsqrtf(vr.w + 1e-5f) * (h[3] - mn.w) + be.w;
    out[i] = o;
}

// ---------------------------------------------------------------------------
extern "C" void kernel_launch(void* const* d_in, const int* in_sizes, int n_in,
                              void* d_out, int out_size, void* d_ws, size_t ws_size,
                              hipStream_t stream) {
    const float* x     = (const float*)d_in[0];
    const float* bw0   = (const float*)d_in[2];
    const float* sw0   = (const float*)d_in[3];
    const float* bw1   = (const float*)d_in[5];
    const float* sw1   = (const float*)d_in[6];
    const float* bw2   = (const float*)d_in[8];
    const float* sw2   = (const float*)d_in[9];
    const float* gamma = (const float*)d_in[10];
    const float* beta  = (const float*)d_in[11];
    const float* mean  = (const float*)d_in[12];
    const float* var   = (const float*)d_in[13];

    char* ws = (char*)d_ws;
    ushort_t* Abuf = (ushort_t*)(ws);
    ushort_t* W0   = (ushort_t*)(ws + 100663296);
    ushort_t* W1   = (ushort_t*)(ws + 103809024);
    ushort_t* W2   = (ushort_t*)(ws + 110100480);
    ushort_t* P    = (ushort_t*)(ws + 113246208);  // 32 MB bf16 partial region
    float*    out  = (float*)d_out;

    const size_t PS = (size_t)8192 * 512;   // L0/L1 partial stride (elements)
    const size_t QS = (size_t)8192 * 256;   // L2 partial stride

    // 1) pack all weights + expand layer-0 input
    prep_kernel<<<4096, 256, 0, stream>>>(bw0, sw0, W0, bw1, sw1, W1,
                                          bw2, sw2, W2, x, Abuf);
    // 2) layer 0 GEMM: K=3072 (48 chunks, 12/split), N=512, SK=4
    {
        dim3 g(32, 4, 4);
        gemm_kernel<<<g, 512, 0, stream>>>(Abuf, W0, P, 8192, 512, 3072, 12);
    }
    // 3) expand h1 = sum(P[0..3]) -> A
    expand_kernel<<<4096, 256, 0, stream>>>(P, PS, Abuf, 8192 * 512 / 4);
    // 4) layer 1 GEMM: K=6144 (96 chunks, 24/split), N=512, SK=4
    {
        dim3 g(32, 4, 4);
        gemm_kernel<<<g, 512, 0, stream>>>(Abuf, W1, P, 8192, 512, 6144, 24);
    }
    // 5) expand h2 = sum(P[0..3]) -> A
    expand_kernel<<<4096, 256, 0, stream>>>(P, PS, Abuf, 8192 * 512 / 4);
    // 6) layer 2 GEMM: K=6144 (96 chunks, 12/split), N=256, SK=8
    {
        dim3 g(32, 2, 8);
        gemm_kernel<<<g, 512, 0, stream>>>(Abuf, W2, P, 8192, 256, 6144, 12);
    }
    // 7) BN + 8-way split-K reduce -> out
    bn_reduce_kernel<<<2048, 256, 0, stream>>>(P, QS, gamma, beta, mean, var,
                                               (float4*)out, 8192 * 256 / 4);
}